// Round 10
// baseline (151.000 us; speedup 1.0000x reference)
//
#include <hip/hip_runtime.h>

#define CH    512
#define BATCH 16
#define HW    3136     // 56*56
#define HW4   784      // HW/4 (float4 per image plane)
#define THRESH 8.0f
#define NBLK  2048     // 8 blocks/CU * 256 CUs -> fully co-resident
#define NCNT  64       // distributed barrier counters
#define CNT_TARGET 32u // NBLK / NCNT

typedef float f4 __attribute__((ext_vector_type(4)));

// Single fused kernel: phase 1 absmax -> distributed release-counter ->
// (gather-duty blocks only) acquire-spin -> plan scan -> NT-store stream.
__global__ __launch_bounds__(256, 8) void fused_kernel(
        const float*  __restrict__ x,
        float*        __restrict__ partial,   // ws: 2048 floats
        unsigned int* __restrict__ cnt,       // ws: 64 uints, zeroed per call
        float*        __restrict__ out,
        float*        __restrict__ out_tail,
        int R) {
    const int w    = blockIdx.x;
    const int tid  = threadIdx.x;
    const int lane = tid & 63;
    const int wv   = tid >> 6;     // wave id (4 waves)

    // ---- phase 1: absmax over 4 planes (c = w & 511, q = w >> 9) --------
    {
        const int c = w & (CH - 1);
        const int q = w >> 9;
        float m = 0.0f;
        for (int bb = 0; bb < 4; ++bb) {
            const int b = q * 4 + bb;
            const f4* src = reinterpret_cast<const f4*>(x) + (size_t)(b * CH + c) * HW4;
            for (int p = tid; p < HW4; p += 256) {
                f4 v = src[p];
                m = fmaxf(m, fmaxf(fmaxf(fabsf(v.x), fabsf(v.y)),
                                   fmaxf(fabsf(v.z), fabsf(v.w))));
            }
        }
        __shared__ float sm[256];
        sm[tid] = m;
        __syncthreads();
        for (int off = 128; off > 0; off >>= 1) {
            if (tid < off) sm[tid] = fmaxf(sm[tid], sm[tid + off]);
            __syncthreads();
        }
        if (tid == 0) {
            partial[c * 4 + q] = sm[0];
            // release: all prior writes (partial) visible before count bump.
            // 64 counter lines, block w -> line w%64 (same-XCD: w%8==line%8).
            __hip_atomic_fetch_add(&cnt[w & (NCNT - 1)], 1u,
                                   __ATOMIC_RELEASE, __HIP_MEMORY_SCOPE_AGENT);
        }
    }

    // blocks with no gather duty retire now (frees wave slots)
    if (w >= R) return;

    // ---- phase 2: acquire-spin until all NBLK producers have released ---
    if (tid < NCNT) {
        int guard = 0;
        while (__hip_atomic_load(&cnt[tid], __ATOMIC_ACQUIRE,
                                 __HIP_MEMORY_SCOPE_AGENT) < CNT_TARGET) {
            __builtin_amdgcn_s_sleep(2);
            if (++guard > (1 << 20)) break;    // anti-hang insurance
        }
    }
    __syncthreads();

    // ---- phase 3: plan scan (R7 verbatim) --------------------------------
    // bijective XCD chunk mapping over [0,R): replica pairs (j, j+1) of one
    // source plane land on the same XCD -> L2-shared reads.
    const int nwg = R;
    const int xcd = w & 7;
    const int q8 = nwg >> 3, r8 = nwg & 7;
    const int j = (xcd < r8 ? xcd * (q8 + 1) : r8 * (q8 + 1) + (xcd - r8) * q8)
                  + (w >> 3);                 // output channel slot

    const int c0 = tid * 2, c1 = c0 + 1;
    f4 p0 = reinterpret_cast<const f4*>(partial)[c0];   // channel c0's 4 partials
    f4 p1 = reinterpret_cast<const f4*>(partial)[c1];
    float m0 = fmaxf(fmaxf(p0.x, p0.y), fmaxf(p0.z, p0.w));
    float m1 = fmaxf(fmaxf(p1.x, p1.y), fmaxf(p1.z, p1.w));
    int T0 = (m0 > THRESH) ? (int)ceilf(m0 * 0.125f) : 0;  // ceil(m/8), exact
    int T1 = (m1 > THRESH) ? (int)ceilf(m1 * 0.125f) : 0;
    const int v = T0 + T1;

    int s = v;                    // wave-inclusive scan (no barriers)
    #pragma unroll
    for (int off = 1; off < 64; off <<= 1) {
        int t2 = __shfl_up(s, off, 64);
        if (lane >= off) s += t2;
    }
    __shared__ int wsum[4];
    if (lane == 63) wsum[wv] = s;
    __syncthreads();
    int woff = 0;
    #pragma unroll
    for (int k = 0; k < 4; ++k) if (k < wv) woff += wsum[k];
    const int excl   = woff + s - v;       // first output slot of channel c0
    const int start0 = excl, start1 = excl + T0;

    __shared__ int sc, sT;
    if (T0 > 0 && j >= start0 && j < start0 + T0) { sc = c0; sT = T0; }
    if (T1 > 0 && j >= start1 && j < start1 + T1) { sc = c1; sT = T1; }

    // block j==0 additionally writes the outlier-id tail (fp32 channel ids)
    if (j == 0) {
        const int o0 = (T0 > 0), o1 = (T1 > 0);
        const int v2 = o0 + o1;
        int s2 = v2;
        #pragma unroll
        for (int off = 1; off < 64; off <<= 1) {
            int t2 = __shfl_up(s2, off, 64);
            if (lane >= off) s2 += t2;
        }
        __shared__ int wsum2[4];
        if (lane == 63) wsum2[wv] = s2;
        __syncthreads();
        int woff2 = 0;
        #pragma unroll
        for (int k = 0; k < 4; ++k) if (k < wv) woff2 += wsum2[k];
        const int ex2 = woff2 + s2 - v2;
        if (o0) out_tail[ex2]      = (float)c0;
        if (o1) out_tail[ex2 + o0] = (float)c1;
    }
    __syncthreads();

    const int   c     = sc;                          // block-uniform
    const float scale = (float)(1.0 / (double)sT);   // numpy f64->f32 rounding

    // ---- phase 4: stream all 16 planes of channel c -> output slot j ----
    const f4* srcb = reinterpret_cast<const f4*>(x)   + (size_t)c * HW4;
    f4*       dstb = reinterpret_cast<f4*>(out)       + (size_t)j * HW4;
    for (int idx = tid; idx < BATCH * HW4; idx += 256) {   // 49 full iters
        const int b = idx / HW4;             // const-div -> magic mul
        f4 vv = srcb[(size_t)b * (CH * HW4 - HW4) + idx];
        vv.x *= scale; vv.y *= scale; vv.z *= scale; vv.w *= scale;
        __builtin_nontemporal_store(vv, &dstb[(size_t)b * ((size_t)(R - 1) * HW4) + idx]);
    }
}

extern "C" void kernel_launch(void* const* d_in, const int* in_sizes, int n_in,
                              void* d_out, int out_size, void* d_ws, size_t ws_size,
                              hipStream_t stream) {
    const float* x = (const float*)d_in[0];
    float* out = (float*)d_out;

    // out_size = 50176*R + n_out,  n_out <= 512 < 50176  -> unique split
    const int plane = BATCH * HW;               // 50176
    const int R     = out_size / plane;         // total replicated channels

    float*        partial = (float*)d_ws;                       // 8 KB
    unsigned int* cnt     = (unsigned int*)((char*)d_ws + 8192); // 256 B

    hipMemsetAsync(cnt, 0, NCNT * sizeof(unsigned int), stream);
    fused_kernel<<<dim3(NBLK), 256, 0, stream>>>(
        x, partial, cnt, out, out + (size_t)R * plane, R);
}

// Round 11
// 66.886 us; speedup vs baseline: 2.2576x; 2.2576x over previous
//
#include <hip/hip_runtime.h>

#define CH    512
#define BATCH 16
#define QB    4        // batch planes per absmax block
#define NQ    (BATCH / QB)
#define HW    3136     // 56*56
#define HW4   784      // HW/4 (float4 per image plane)
#define THRESH 8.0f

typedef float f4 __attribute__((ext_vector_type(4)));

// ---- Kernel 1: partial[c*NQ+q] = max|x[b in q*QB.., c, :, :]| -----------
__global__ __launch_bounds__(256) void absmax_kernel(const float* __restrict__ x,
                                                     float* __restrict__ partial) {
    const int c   = blockIdx.x;
    const int q   = blockIdx.y;
    const int tid = threadIdx.x;
    float m = 0.0f;
    for (int bb = 0; bb < QB; ++bb) {
        const int b = q * QB + bb;
        const f4* src = reinterpret_cast<const f4*>(x) + (size_t)(b * CH + c) * HW4;
        for (int p = tid; p < HW4; p += 256) {
            f4 v = src[p];
            m = fmaxf(m, fmaxf(fmaxf(fabsf(v.x), fabsf(v.y)),
                               fmaxf(fabsf(v.z), fabsf(v.w))));
        }
    }
    __shared__ float sm[256];
    sm[tid] = m;
    __syncthreads();
    for (int off = 128; off > 0; off >>= 1) {
        if (tid < off) sm[tid] = fmaxf(sm[tid], sm[tid + off]);
        __syncthreads();
    }
    if (tid == 0) partial[c * NQ + q] = sm[0];
}

// ---- Kernel 2: one block (512 thr, 8 waves) per output channel j --------
// 1030 blocks * 8 waves = 4 blocks/CU -> FULL 32 waves/CU (R7 had 16).
__global__ __launch_bounds__(512) void gather_kernel(const float* __restrict__ x,
                                                     const float* __restrict__ partial,
                                                     float* __restrict__ out,
                                                     float* __restrict__ out_tail,
                                                     int R) {
    // bijective XCD chunk mapping (8 XCDs): replica pairs (j, j+1) of one
    // source plane land in the same chunk -> same XCD -> L2-shared reads.
    const int nwg  = gridDim.x;
    const int orig = blockIdx.x;
    const int xcd  = orig & 7;
    const int q8 = nwg >> 3, r8 = nwg & 7;
    const int j = (xcd < r8 ? xcd * (q8 + 1) : r8 * (q8 + 1) + (xcd - r8) * q8)
                  + (orig >> 3);           // output channel slot

    const int tid  = threadIdx.x;   // 0..511
    const int lane = tid & 63;
    const int wv   = tid >> 6;      // wave id (8 waves)

    // --- plan (once per block): thread t owns channel c = t --------------
    f4 pp = reinterpret_cast<const f4*>(partial)[tid];  // channel's 4 partials
    float m = fmaxf(fmaxf(pp.x, pp.y), fmaxf(pp.z, pp.w));
    int T = (m > THRESH) ? (int)ceilf(m * 0.125f) : 0;  // ceil(m/8), exact

    int s = T;                      // wave-inclusive scan (no barriers)
    #pragma unroll
    for (int off = 1; off < 64; off <<= 1) {
        int t2 = __shfl_up(s, off, 64);
        if (lane >= off) s += t2;
    }
    __shared__ int wsum[8];
    if (lane == 63) wsum[wv] = s;
    __syncthreads();
    int woff = 0;
    #pragma unroll
    for (int k = 0; k < 8; ++k) if (k < wv) woff += wsum[k];
    const int start = woff + s - T;        // first output slot of channel t

    __shared__ int sc, sT;
    if (T > 0 && j >= start && j < start + T) { sc = tid; sT = T; }

    // block j==0 additionally writes the outlier-id tail (fp32 channel ids)
    if (j == 0) {
        const int o = (T > 0) ? 1 : 0;
        int s2 = o;
        #pragma unroll
        for (int off = 1; off < 64; off <<= 1) {
            int t2 = __shfl_up(s2, off, 64);
            if (lane >= off) s2 += t2;
        }
        __shared__ int wsum2[8];
        if (lane == 63) wsum2[wv] = s2;
        __syncthreads();
        int woff2 = 0;
        #pragma unroll
        for (int k = 0; k < 8; ++k) if (k < wv) woff2 += wsum2[k];
        if (o) out_tail[woff2 + s2 - o] = (float)tid;
    }
    __syncthreads();

    const int   c     = sc;                          // block-uniform
    const float scale = (float)(1.0 / (double)sT);   // numpy f64->f32 rounding

    // stream all BATCH planes of channel c -> output slot j, flattened loop
    const f4* srcb = reinterpret_cast<const f4*>(x)   + (size_t)c * HW4;
    f4*       dstb = reinterpret_cast<f4*>(out)       + (size_t)j * HW4;
    for (int idx = tid; idx < BATCH * HW4; idx += 512) {
        const int b = idx / HW4;             // const-div -> magic mul
        f4 vv = srcb[(size_t)b * (CH * HW4 - HW4) + idx];
        vv.x *= scale; vv.y *= scale; vv.z *= scale; vv.w *= scale;
        __builtin_nontemporal_store(vv, &dstb[(size_t)b * ((size_t)(R - 1) * HW4) + idx]);
    }
}

extern "C" void kernel_launch(void* const* d_in, const int* in_sizes, int n_in,
                              void* d_out, int out_size, void* d_ws, size_t ws_size,
                              hipStream_t stream) {
    const float* x = (const float*)d_in[0];
    float* out = (float*)d_out;

    // out_size = 50176*R + n_out,  n_out <= 512 < 50176  -> unique split
    const int plane = BATCH * HW;               // 50176
    const int R     = out_size / plane;         // total replicated channels

    float* partial = (float*)d_ws;              // CH*NQ floats (8 KB)

    absmax_kernel<<<dim3(CH, NQ), 256, 0, stream>>>(x, partial);
    if (R > 0) {
        gather_kernel<<<dim3(R), 512, 0, stream>>>(
            x, partial, out, out + (size_t)R * plane, R);
    }
}

// Round 12
// 65.354 us; speedup vs baseline: 2.3105x; 1.0234x over previous
//
#include <hip/hip_runtime.h>

#define CH    512
#define BATCH 16
#define QB    4        // batch planes per absmax block
#define NQ    (BATCH / QB)
#define HW    3136     // 56*56
#define HW4   784      // HW/4 (float4 per image plane)
#define THRESH 8.0f

typedef float f4 __attribute__((ext_vector_type(4)));

// ---- Kernel 1: partial[c*NQ+q] = max|x[b in q*QB.., c, :, :]| -----------
__global__ __launch_bounds__(256) void absmax_kernel(const float* __restrict__ x,
                                                     float* __restrict__ partial) {
    const int c   = blockIdx.x;
    const int q   = blockIdx.y;
    const int tid = threadIdx.x;
    float m = 0.0f;
    for (int bb = 0; bb < QB; ++bb) {
        const int b = q * QB + bb;
        const f4* src = reinterpret_cast<const f4*>(x) + (size_t)(b * CH + c) * HW4;
        for (int p = tid; p < HW4; p += 256) {
            f4 v = src[p];
            m = fmaxf(m, fmaxf(fmaxf(fabsf(v.x), fabsf(v.y)),
                               fmaxf(fabsf(v.z), fabsf(v.w))));
        }
    }
    __shared__ float sm[256];
    sm[tid] = m;
    __syncthreads();
    for (int off = 128; off > 0; off >>= 1) {
        if (tid < off) sm[tid] = fmaxf(sm[tid], sm[tid + off]);
        __syncthreads();
    }
    if (tid == 0) partial[c * NQ + q] = sm[0];
}

// ---- Kernel 2: one block per output channel j; streams all 16 batches ---
__global__ __launch_bounds__(256) void gather_kernel(const float* __restrict__ x,
                                                     const float* __restrict__ partial,
                                                     float* __restrict__ out,
                                                     float* __restrict__ out_tail,
                                                     int R) {
    // bijective XCD chunk mapping (8 XCDs): replica pairs (j, j+1) of one
    // source plane land in the same chunk -> same XCD -> L2-shared reads.
    const int nwg  = gridDim.x;
    const int orig = blockIdx.x;
    const int xcd  = orig & 7;
    const int q8 = nwg >> 3, r8 = nwg & 7;
    const int j = (xcd < r8 ? xcd * (q8 + 1) : r8 * (q8 + 1) + (xcd - r8) * q8)
                  + (orig >> 3);           // output channel slot

    const int tid  = threadIdx.x;
    const int lane = tid & 63;
    const int w    = tid >> 6;    // wave id (4 waves)

    // --- plan (once per block): thread t owns channels c0=2t, c1=2t+1 ----
    const int c0 = tid * 2, c1 = c0 + 1;
    f4 p0 = reinterpret_cast<const f4*>(partial)[tid * 2];
    f4 p1 = reinterpret_cast<const f4*>(partial)[tid * 2 + 1];
    float m0 = fmaxf(fmaxf(p0.x, p0.y), fmaxf(p0.z, p0.w));
    float m1 = fmaxf(fmaxf(p1.x, p1.y), fmaxf(p1.z, p1.w));
    int T0 = (m0 > THRESH) ? (int)ceilf(m0 * 0.125f) : 0;  // ceil(m/8), exact
    int T1 = (m1 > THRESH) ? (int)ceilf(m1 * 0.125f) : 0;
    const int v = T0 + T1;

    int s = v;                    // wave-inclusive scan (no barriers)
    #pragma unroll
    for (int off = 1; off < 64; off <<= 1) {
        int t2 = __shfl_up(s, off, 64);
        if (lane >= off) s += t2;
    }
    __shared__ int wsum[4];
    if (lane == 63) wsum[w] = s;
    __syncthreads();
    int woff = 0;
    #pragma unroll
    for (int k = 0; k < 4; ++k) if (k < w) woff += wsum[k];
    const int excl   = woff + s - v;       // first output slot of channel c0
    const int start0 = excl, start1 = excl + T0;

    __shared__ int sc, sT;
    if (T0 > 0 && j >= start0 && j < start0 + T0) { sc = c0; sT = T0; }
    if (T1 > 0 && j >= start1 && j < start1 + T1) { sc = c1; sT = T1; }

    // block j==0 additionally writes the outlier-id tail (fp32 channel ids)
    if (j == 0) {
        const int o0 = (T0 > 0), o1 = (T1 > 0);
        const int v2 = o0 + o1;
        int s2 = v2;
        #pragma unroll
        for (int off = 1; off < 64; off <<= 1) {
            int t2 = __shfl_up(s2, off, 64);
            if (lane >= off) s2 += t2;
        }
        __shared__ int wsum2[4];
        if (lane == 63) wsum2[w] = s2;
        __syncthreads();
        int woff2 = 0;
        #pragma unroll
        for (int k = 0; k < 4; ++k) if (k < w) woff2 += wsum2[k];
        const int ex2 = woff2 + s2 - v2;
        if (o0) out_tail[ex2]      = (float)c0;
        if (o1) out_tail[ex2 + o0] = (float)c1;
    }
    __syncthreads();

    const int   c     = sc;                          // block-uniform
    const float scale = (float)(1.0 / (double)sT);   // numpy f64->f32 rounding

    // stream all BATCH planes of channel c -> output slot j, flattened loop
    const f4* srcb = reinterpret_cast<const f4*>(x)   + (size_t)c * HW4;
    f4*       dstb = reinterpret_cast<f4*>(out)       + (size_t)j * HW4;
    for (int idx = tid; idx < BATCH * HW4; idx += 256) {
        const int b = idx / HW4;             // const-div -> magic mul
        f4 vv = srcb[(size_t)b * (CH * HW4 - HW4) + idx];
        vv.x *= scale; vv.y *= scale; vv.z *= scale; vv.w *= scale;
        __builtin_nontemporal_store(vv, &dstb[(size_t)b * ((size_t)(R - 1) * HW4) + idx]);
    }
}

extern "C" void kernel_launch(void* const* d_in, const int* in_sizes, int n_in,
                              void* d_out, int out_size, void* d_ws, size_t ws_size,
                              hipStream_t stream) {
    const float* x = (const float*)d_in[0];
    float* out = (float*)d_out;

    // out_size = 50176*R + n_out,  n_out <= 512 < 50176  -> unique split
    const int plane = BATCH * HW;               // 50176
    const int R     = out_size / plane;         // total replicated channels

    float* partial = (float*)d_ws;              // CH*NQ floats (8 KB)

    absmax_kernel<<<dim3(CH, NQ), 256, 0, stream>>>(x, partial);
    if (R > 0) {
        gather_kernel<<<dim3(R), 256, 0, stream>>>(
            x, partial, out, out + (size_t)R * plane, R);
    }
}